// Round 14
// baseline (161.990 us; speedup 1.0000x reference)
//
#include <hip/hip_runtime.h>

#define SEQ 2048
#define D_MODEL 1024
#define NTOK 4096
#define PROW 4096
#define DH 64
#define LN_EPS 1e-5f
#define SHEP_EPS 1e-4f

typedef __attribute__((ext_vector_type(8))) short bf16x8;
typedef __attribute__((ext_vector_type(4))) short s16x4;
typedef __attribute__((ext_vector_type(4))) float f32x4;

__device__ __forceinline__ unsigned short f2bf(float f) {
  union { float f; unsigned u; } v; v.f = f;
  unsigned r = v.u + 0x7fffu + ((v.u >> 16) & 1u);
  return (unsigned short)(r >> 16);
}
__device__ __forceinline__ float bf2f(unsigned short s) {
  union { unsigned u; float f; } v; v.u = ((unsigned)s) << 16;
  return v.f;
}
__device__ __forceinline__ void gload16(const void* g, void* l) {
  __builtin_amdgcn_global_load_lds(
      (const __attribute__((address_space(1))) unsigned int*)g,
      (__attribute__((address_space(3))) unsigned int*)l, 16, 0, 0);
}
__device__ __forceinline__ void gload4(const void* g, void* l) {
  __builtin_amdgcn_global_load_lds(
      (const __attribute__((address_space(1))) unsigned int*)g,
      (__attribute__((address_space(3))) unsigned int*)l, 4, 0, 0);
}
__device__ __forceinline__ unsigned cvt_pk_bf16(float lo, float hi) {
  unsigned r;
  asm("v_cvt_pk_bf16_f32 %0, %1, %2" : "=v"(r) : "v"(lo), "v"(hi));
  return r;
}
#define MFMA16(a, b, c) __builtin_amdgcn_mfma_f32_16x16x32_bf16(a, b, c, 0, 0, 0)

// XCD-aware bijective block swizzle (T1): valid since nwg % 8 == 0.
__device__ __forceinline__ int xcd_swizzle(int linear, int nwg) {
  int cpx = nwg >> 3;
  return (linear & 7) * cpx + (linear >> 3);
}

// ---------------- LayerNorm: f32 row -> bf16 row ----------------
__global__ __launch_bounds__(256) void ln_kernel(const float* __restrict__ X,
                                                 unsigned short* __restrict__ Xn) {
  int row = blockIdx.x, tid = threadIdx.x;
  const float4* xr = (const float4*)(X + (size_t)row * D_MODEL);
  float4 v = xr[tid];
  float s = v.x + v.y + v.z + v.w;
  float s2 = v.x * v.x + v.y * v.y + v.z * v.z + v.w * v.w;
#pragma unroll
  for (int off = 32; off > 0; off >>= 1) {
    s += __shfl_down(s, off);
    s2 += __shfl_down(s2, off);
  }
  __shared__ float red[8];
  __shared__ float mb[2];
  int wv = tid >> 6;
  if ((tid & 63) == 0) { red[wv] = s; red[4 + wv] = s2; }
  __syncthreads();
  if (tid == 0) {
    float ts = red[0] + red[1] + red[2] + red[3];
    float t2 = red[4] + red[5] + red[6] + red[7];
    float mu = ts * (1.f / D_MODEL);
    float var = t2 * (1.f / D_MODEL) - mu * mu;
    mb[0] = mu;
    mb[1] = rsqrtf(var + LN_EPS);
  }
  __syncthreads();
  float mu = mb[0], rs = mb[1];
  s16x4 o;
  o[0] = (short)f2bf((v.x - mu) * rs);
  o[1] = (short)f2bf((v.y - mu) * rs);
  o[2] = (short)f2bf((v.z - mu) * rs);
  o[3] = (short)f2bf((v.w - mu) * rs);
  ((s16x4*)(Xn + (size_t)row * D_MODEL))[tid] = o;
}

// ---------------- fused f32 -> bf16 convert (W_in then W_out, contiguous dest) ----------------
__global__ __launch_bounds__(256) void cvt_both_kernel(const float* __restrict__ Win,
                                                       const float* __restrict__ Wout,
                                                       unsigned short* __restrict__ dst) {
  const int N1 = (4096 * 1024) / 4;
  const int N2 = (1024 * 1024) / 4;
  int i = blockIdx.x * 256 + threadIdx.x;
  if (i >= N1 + N2) return;
  float4 v = (i < N1) ? ((const float4*)Win)[i] : ((const float4*)Wout)[i - N1];
  s16x4 o;
  o[0] = (short)f2bf(v.x);
  o[1] = (short)f2bf(v.y);
  o[2] = (short)f2bf(v.z);
  o[3] = (short)f2bf(v.w);
  ((s16x4*)dst)[i] = o;
}

// ---------------- GEMM (NT, bf16 in, bf16 out + bias) : P = Xn*Wi^T + b ----------------
__global__ __launch_bounds__(256) void gemm_p_kernel(
    const unsigned short* __restrict__ A, const unsigned short* __restrict__ B,
    const float* __restrict__ bias, unsigned short* __restrict__ C,
    int M, int N, int K) {
  __shared__ __align__(16) unsigned short sA[128 * 64];
  __shared__ __align__(16) unsigned short sB[128 * 64];
  int tid = threadIdx.x;
  int nwg = gridDim.x * gridDim.y;
  int swz = xcd_swizzle(blockIdx.y * gridDim.x + blockIdx.x, nwg);
  int m0 = (swz / gridDim.x) * 128, n0 = (swz % gridDim.x) * 128;
  int wv = tid >> 6, lane = tid & 63;
  int wr = wv >> 1, wc = wv & 1;
  int lr = lane & 15, lq = lane >> 4;
  f32x4 acc[4][4] = {};
  for (int k0 = 0; k0 < K; k0 += 64) {
#pragma unroll
    for (int it = 0; it < 4; it++) {
      int c = tid + it * 256;
      int row = c >> 3;
      int col = ((c & 7) ^ (row & 7)) * 8;
      gload16(A + (size_t)(m0 + row) * K + k0 + col, (char*)sA + c * 16);
      gload16(B + (size_t)(n0 + row) * K + k0 + col, (char*)sB + c * 16);
    }
    __syncthreads();
#pragma unroll
    for (int ks = 0; ks < 2; ks++) {
      bf16x8 af[4], bfr[4];
#pragma unroll
      for (int m = 0; m < 4; m++) {
        int row = wr * 64 + m * 16 + lr;
        af[m] = *(const bf16x8*)((const char*)sA + row * 128 +
                                 (((ks * 4 + lq) ^ (lr & 7)) * 16));
      }
#pragma unroll
      for (int n = 0; n < 4; n++) {
        int row = wc * 64 + n * 16 + lr;
        bfr[n] = *(const bf16x8*)((const char*)sB + row * 128 +
                                  (((ks * 4 + lq) ^ (lr & 7)) * 16));
      }
#pragma unroll
      for (int m = 0; m < 4; m++)
#pragma unroll
        for (int n = 0; n < 4; n++)
          acc[m][n] = MFMA16(af[m], bfr[n], acc[m][n]);
    }
    __syncthreads();
  }
#pragma unroll
  for (int m = 0; m < 4; m++) {
    int row = m0 + wr * 64 + m * 16 + lq * 4;
#pragma unroll
    for (int n = 0; n < 4; n++) {
      int col = n0 + wc * 64 + n * 16 + lr;
      float bv = bias[col];
#pragma unroll
      for (int r = 0; r < 4; r++)
        C[(size_t)(row + r) * N + col] = f2bf(acc[m][n][r] + bv);
    }
  }
}

// ---------------- GEMM (NT) + residual + bias, f32 out : out = X + O*Wo^T + b ----------------
__global__ __launch_bounds__(256) void gemm_out_kernel(
    const unsigned short* __restrict__ A, const unsigned short* __restrict__ B,
    const float* __restrict__ bias, const float* __restrict__ Xres,
    float* __restrict__ Out, int M, int N, int K) {
  __shared__ __align__(16) unsigned short sA[128 * 64];
  __shared__ __align__(16) unsigned short sB[128 * 64];
  int tid = threadIdx.x;
  int nwg = gridDim.x * gridDim.y;
  int swz = xcd_swizzle(blockIdx.y * gridDim.x + blockIdx.x, nwg);
  int m0 = (swz / gridDim.x) * 128, n0 = (swz % gridDim.x) * 128;
  int wv = tid >> 6, lane = tid & 63;
  int wr = wv >> 1, wc = wv & 1;
  int lr = lane & 15, lq = lane >> 4;
  f32x4 acc[4][4] = {};
  for (int k0 = 0; k0 < K; k0 += 64) {
#pragma unroll
    for (int it = 0; it < 4; it++) {
      int c = tid + it * 256;
      int row = c >> 3;
      int col = ((c & 7) ^ (row & 7)) * 8;
      gload16(A + (size_t)(m0 + row) * K + k0 + col, (char*)sA + c * 16);
      gload16(B + (size_t)(n0 + row) * K + k0 + col, (char*)sB + c * 16);
    }
    __syncthreads();
#pragma unroll
    for (int ks = 0; ks < 2; ks++) {
      bf16x8 af[4], bfr[4];
#pragma unroll
      for (int m = 0; m < 4; m++) {
        int row = wr * 64 + m * 16 + lr;
        af[m] = *(const bf16x8*)((const char*)sA + row * 128 +
                                 (((ks * 4 + lq) ^ (lr & 7)) * 16));
      }
#pragma unroll
      for (int n = 0; n < 4; n++) {
        int row = wc * 64 + n * 16 + lr;
        bfr[n] = *(const bf16x8*)((const char*)sB + row * 128 +
                                  (((ks * 4 + lq) ^ (lr & 7)) * 16));
      }
#pragma unroll
      for (int m = 0; m < 4; m++)
#pragma unroll
        for (int n = 0; n < 4; n++)
          acc[m][n] = MFMA16(af[m], bfr[n], acc[m][n]);
    }
    __syncthreads();
  }
#pragma unroll
  for (int m = 0; m < 4; m++) {
    int row = m0 + wr * 64 + m * 16 + lq * 4;
#pragma unroll
    for (int n = 0; n < 4; n++) {
      int col = n0 + wc * 64 + n * 16 + lr;
      float bv = bias[col];
#pragma unroll
      for (int r = 0; r < 4; r++) {
        size_t idx = (size_t)(row + r) * N + col;
        Out[idx] = Xres[idx] + acc[m][n][r] + bv;
      }
    }
  }
}

// ---------------- V transpose: P's V slice [t][c] -> Vt[bh][c][t] ----------------
__global__ __launch_bounds__(256) void transv_kernel(const unsigned short* __restrict__ P,
                                                     unsigned short* __restrict__ Vt) {
  int kt = blockIdx.x;
  int bh = blockIdx.y;
  int b = bh >> 4, h = bh & 15;
  __shared__ unsigned short sT[64][72];
  int tid = threadIdx.x;
  const unsigned short* vbase = P + ((size_t)(b * SEQ + kt * 64)) * PROW + h * 256 + 128;
#pragma unroll
  for (int it = 0; it < 2; it++) {
    int c = tid + it * 256;
    int k = c >> 3, c0 = (c & 7) * 8;
    uint4 u = *(const uint4*)(vbase + (size_t)k * PROW + c0);
    unsigned e[4] = {u.x, u.y, u.z, u.w};
#pragma unroll
    for (int j = 0; j < 4; j++) {
      sT[c0 + 2 * j][k] = (unsigned short)(e[j] & 0xffffu);
      sT[c0 + 2 * j + 1][k] = (unsigned short)(e[j] >> 16);
    }
  }
  __syncthreads();
  unsigned short* obase = Vt + (size_t)bh * 64 * SEQ + kt * 64;
#pragma unroll
  for (int it = 0; it < 2; it++) {
    int cc = tid + it * 256;
    int crow = cc >> 3, k0 = (cc & 7) * 8;
    uint4 o;
    unsigned short e[8];
#pragma unroll
    for (int j = 0; j < 8; j++) e[j] = sT[crow][k0 + j];
    o.x = (unsigned)e[0] | ((unsigned)e[1] << 16);
    o.y = (unsigned)e[2] | ((unsigned)e[3] << 16);
    o.z = (unsigned)e[4] | ((unsigned)e[5] << 16);
    o.w = (unsigned)e[6] | ((unsigned)e[7] << 16);
    *(uint4*)(obase + (size_t)crow * SEQ + k0) = o;
  }
}

// ---------------- row norms of Q and K slices (from bf16 P) ----------------
__global__ __launch_bounds__(256) void norms_kernel(const unsigned short* __restrict__ P,
                                                    float* __restrict__ nrm) {
  int id = blockIdx.x * 256 + threadIdx.x;
  int bh = id >> 12;
  int which = (id >> 11) & 1;
  int t = id & 2047;
  int b = bh >> 4, h = bh & 15;
  const unsigned short* p = P + ((size_t)(b * SEQ + t)) * PROW + h * 256 + which * 64;
  const uint4* pv = (const uint4*)p;
  float acc = 0.f;
#pragma unroll
  for (int i = 0; i < 8; i++) {
    uint4 u = pv[i];
    unsigned arr[4] = {u.x, u.y, u.z, u.w};
#pragma unroll
    for (int j = 0; j < 4; j++) {
      float lo = __uint_as_float(arr[j] << 16);
      float hi = __uint_as_float(arr[j] & 0xffff0000u);
      acc += lo * lo + hi * hi;
    }
  }
  nrm[(size_t)(bh * 2 + which) * SEQ + t] = acc;
}

// ---------------- Shepard attention, KEY-SPLIT (4 waves x 32 q-rows, 16 key-tiles/block) ----------------
// r9-certified 4wx32q counted-vmcnt core + r10/r11-certified Q-from-global.
// blockIdx.z = split s in {0,1}: keys [s*1024, s*1024+1024). Writes PARTIAL
// num (bf16: split0 -> numP0 flat [like O], split1 -> P's dead V-slice) and
// partial den (f32 -> denP). Grid 1024 -> 3 blocks/CU (LDS ~48.6KB) = 12
// waves/CU of 32q-waves: halved per-q LDS traffic vs 16q waves.
__global__ __launch_bounds__(256) void attn_split_kernel(
    const unsigned short* __restrict__ P, const unsigned short* __restrict__ Vt,
    const float* __restrict__ nrm, unsigned short* __restrict__ numP0,
    unsigned short* __restrict__ numP1base, float* __restrict__ denP) {
  const int NTL = 16;  // key-tiles per split
  int qt = blockIdx.x, bh = blockIdx.y, sp = blockIdx.z;
  int kt0 = sp * NTL;
  int b = bh >> 4, h = bh & 15;
  int tid = threadIdx.x;
  int w = tid >> 6, lane = tid & 63;
  int lr = lane & 15, lq = lane >> 4;

  __shared__ __align__(16) unsigned short sK[2][64 * 64];
  __shared__ __align__(16) unsigned short sV[2][64 * 64];
  __shared__ __align__(16) unsigned short sW[128 * 64];  // wave-private 32-row slabs
  __shared__ __align__(16) float sK2[2][64];

  const unsigned short* qbase = P + ((size_t)(b * SEQ + qt * 128)) * PROW + h * 256;
  const unsigned short* kbase = P + ((size_t)(b * SEQ)) * PROW + h * 256 + 64;
  const unsigned short* vtb = Vt + (size_t)bh * 64 * SEQ;
  const float* k2base = nrm + (size_t)(bh * 2 + 1) * SEQ;

  auto stage_kv = [&](int t, int buf) {
#pragma unroll
    for (int it = 0; it < 2; it++) {
      int c = tid + it * 256;
      int row = c >> 3;
      int col = ((c & 7) ^ (row & 7)) * 8;
      gload16(kbase + (size_t)(t * 64 + row) * PROW + col, (char*)&sK[buf][0] + c * 16);
      gload16(vtb + (size_t)row * SEQ + t * 64 + col, (char*)&sV[buf][0] + c * 16);
    }
    if (tid < 64) gload4(k2base + t * 64 + tid, (char*)&sK2[buf][0] + tid * 4);
  };

  // ---- prologue: stage tiles kt0,kt0+1; Q frags + q2 from global; full drain
  stage_kv(kt0 + 0, 0);
  stage_kv(kt0 + 1, 1);
  bf16x8 qf[2][2];
#pragma unroll
  for (int fq = 0; fq < 2; fq++) {
    int row = 32 * w + 16 * fq + lr;
#pragma unroll
    for (int ks = 0; ks < 2; ks++)
      qf[fq][ks] = *(const bf16x8*)(qbase + (size_t)row * PROW + ks * 64 + 8 * lq);
  }
  float q2f0 = nrm[(size_t)(bh * 2) * SEQ + qt * 128 + 32 * w + lr];
  float q2f1 = nrm[(size_t)(bh * 2) * SEQ + qt * 128 + 32 * w + 16 + lr];
  asm volatile("" ::"v"(q2f0), "v"(q2f1));  // materialize before counted region
  __syncthreads();                          // full drain: counts start at 0

  f32x4 num[2][4] = {};
  float den[2] = {0.f, 0.f};
  char* wrow0 = (char*)sW + (32 * w + lr) * 128;
  char* wrow1 = (char*)sW + (32 * w + 16 + lr) * 128;

  for (int t = 0; t < NTL; t++) {
    int cur = t & 1;
    // stage(t) complete; stage(t+1) (4|5 ops/wave) stays in flight
    if (t == NTL - 1)
      asm volatile("s_waitcnt vmcnt(0)" ::: "memory");
    else if (w == 0)
      asm volatile("s_waitcnt vmcnt(5)" ::: "memory");
    else
      asm volatile("s_waitcnt vmcnt(4)" ::: "memory");
    __builtin_amdgcn_sched_barrier(0);
    __builtin_amdgcn_s_barrier();
    __builtin_amdgcn_sched_barrier(0);

    // S^T[k][q] = K . Q^T (K fragments shared across both q-frags)
    f32x4 st[2][4] = {};
    __builtin_amdgcn_s_setprio(1);
#pragma unroll
    for (int fk = 0; fk < 4; fk++) {
      int row = 16 * fk + lr;
      const char* krow = (const char*)&sK[cur][0] + row * 128;
      bf16x8 kf0 = *(const bf16x8*)(krow + ((lq * 16) ^ ((row & 7) << 4)));
      bf16x8 kf1 = *(const bf16x8*)(krow + ((64 + lq * 16) ^ ((row & 7) << 4)));
      st[0][fk] = MFMA16(kf0, qf[0][0], st[0][fk]);
      st[0][fk] = MFMA16(kf1, qf[0][1], st[0][fk]);
      st[1][fk] = MFMA16(kf0, qf[1][0], st[1][fk]);
      st[1][fk] = MFMA16(kf1, qf[1][1], st[1][fk]);
    }
    __builtin_amdgcn_s_setprio(0);

    // weights: w = rcp(max(q2+k2-2*st, 1e-8)); accumulate den; pack to W slab
#pragma unroll
    for (int fk = 0; fk < 4; fk++) {
      f32x4 k2v = *(const f32x4*)&sK2[cur][16 * fk + 4 * lq];
#pragma unroll
      for (int fq = 0; fq < 2; fq++) {
        float q2 = fq ? q2f1 : q2f0;
        float w0 = __builtin_amdgcn_rcpf(fmaxf(fmaf(-2.f, st[fq][fk][0], q2 + k2v[0]), 1e-8f));
        float w1 = __builtin_amdgcn_rcpf(fmaxf(fmaf(-2.f, st[fq][fk][1], q2 + k2v[1]), 1e-8f));
        float w2 = __builtin_amdgcn_rcpf(fmaxf(fmaf(-2.f, st[fq][fk][2], q2 + k2v[2]), 1e-8f));
        float w3 = __builtin_amdgcn_rcpf(fmaxf(fmaf(-2.f, st[fq][fk][3], q2 + k2v[3]), 1e-8f));
        den[fq] += (w0 + w1) + (w2 + w3);
        uint2 pp;
        pp.x = cvt_pk_bf16(w0, w1);
        pp.y = cvt_pk_bf16(w2, w3);
        char* wr = fq ? wrow1 : wrow0;
        *(uint2*)(wr + ((32 * fk + 8 * lq) ^ ((lr & 7) << 4))) = pp;
      }
    }

    // PV: num += W.V^T (V fragments shared across q-frags)
    __builtin_amdgcn_s_setprio(1);
#pragma unroll
    for (int ks = 0; ks < 2; ks++) {
      bf16x8 aw0 = *(const bf16x8*)(wrow0 + ((64 * ks + 16 * lq) ^ ((lr & 7) << 4)));
      bf16x8 aw1 = *(const bf16x8*)(wrow1 + ((64 * ks + 16 * lq) ^ ((lr & 7) << 4)));
#pragma unroll
      for (int fn = 0; fn < 4; fn++) {
        int row = 16 * fn + lr;
        bf16x8 bv = *(const bf16x8*)((const char*)&sV[cur][0] + row * 128 +
                                     ((64 * ks + 16 * lq) ^ ((row & 7) << 4)));
        num[0][fn] = MFMA16(aw0, bv, num[0][fn]);
        num[1][fn] = MFMA16(aw1, bv, num[1][fn]);
      }
    }
    __builtin_amdgcn_s_setprio(0);

    __builtin_amdgcn_sched_barrier(0);
    __builtin_amdgcn_s_barrier();  // all waves done reading buffer cur
    __builtin_amdgcn_sched_barrier(0);
    if (t + 2 < NTL) stage_kv(kt0 + t + 2, cur);  // refill freed buffer
  }

  // partial den: butterfly over lq groups -> all lanes hold this split's den
#pragma unroll
  for (int fq = 0; fq < 2; fq++) {
    den[fq] += __shfl_xor(den[fq], 16);
    den[fq] += __shfl_xor(den[fq], 32);
  }
  size_t denBase = ((size_t)(sp * 32 + bh)) * SEQ + qt * 128;
  if (lq == 0) {
    denP[denBase + 32 * w + lr] = den[0];
    denP[denBase + 32 * w + 16 + lr] = den[1];
  }

  // partial num (bf16): split0 -> numP0 (flat, O layout); split1 -> P V-slice
#pragma unroll
  for (int fq = 0; fq < 2; fq++) {
#pragma unroll
    for (int fn = 0; fn < 4; fn++) {
      int c = 16 * fn + lr;
#pragma unroll
      for (int r = 0; r < 4; r++) {
        int ql = 32 * w + 16 * fq + 4 * lq + r;
        unsigned short val = f2bf(num[fq][fn][r]);
        size_t tok = (size_t)(b * SEQ + qt * 128 + ql);
        if (sp == 0)
          numP0[tok * D_MODEL + h * DH + c] = val;
        else
          numP1base[tok * PROW + h * 256 + 128 + c] = val;
      }
    }
  }
}

// ---------------- combine: O = G * (n0+n1) / (d0+d1+eps), in-place over numP0 ----------------
__global__ __launch_bounds__(256) void combine_kernel(
    unsigned short* __restrict__ numP0, const unsigned short* __restrict__ P,
    const float* __restrict__ denP) {
  int gid = blockIdx.x * 256 + threadIdx.x;  // 4096*1024/8 = 524288 threads
  int tok = gid >> 7;                        // token 0..4095
  int grp = gid & 127;
  int h = grp >> 3, c0 = (grp & 7) * 8;
  int b = tok >> 11, tseq = tok & 2047;
  int bh = b * 16 + h;

  float d0 = denP[(size_t)bh * SEQ + tseq];
  float d1 = denP[(size_t)(32 + bh) * SEQ + tseq];
  float rdv = __builtin_amdgcn_rcpf(d0 + d1 + SHEP_EPS);

  unsigned short* p0 = numP0 + (size_t)tok * D_MODEL + h * DH + c0;
  const unsigned short* p1 = P + (size_t)tok * PROW + h * 256 + 128 + c0;
  const unsigned short* pg = P + (size_t)tok * PROW + h * 256 + 192 + c0;
  uint4 u0 = *(const uint4*)p0;
  uint4 u1 = *(const uint4*)p1;
  uint4 ug = *(const uint4*)pg;
  unsigned a0[4] = {u0.x, u0.y, u0.z, u0.w};
  unsigned a1[4] = {u1.x, u1.y, u1.z, u1.w};
  unsigned ag[4] = {ug.x, ug.y, ug.z, ug.w};
  uint4 out;
  unsigned ov[4];
#pragma unroll
  for (int j = 0; j < 4; j++) {
    float n_lo = __uint_as_float(a0[j] << 16) + __uint_as_float(a1[j] << 16);
    float n_hi = __uint_as_float(a0[j] & 0xffff0000u) + __uint_as_float(a1[j] & 0xffff0000u);
    float g_lo = __uint_as_float(ag[j] << 16);
    float g_hi = __uint_as_float(ag[j] & 0xffff0000u);
    ov[j] = cvt_pk_bf16(g_lo * n_lo * rdv, g_hi * n_hi * rdv);
  }
  out.x = ov[0]; out.y = ov[1]; out.z = ov[2]; out.w = ov[3];
  *(uint4*)p0 = out;
}

// ---------------- Shepard attention FALLBACK (r11, 8 waves x 16 q-rows, 62.8us) ----------------
__global__ __launch_bounds__(512) void attn_kernel(
    const unsigned short* __restrict__ P, const unsigned short* __restrict__ Vt,
    const float* __restrict__ nrm, unsigned short* __restrict__ O) {
  const int NT = SEQ / 64;
  int qt = blockIdx.x, bh = blockIdx.y;
  int b = bh >> 4, h = bh & 15;
  int tid = threadIdx.x;
  int w = tid >> 6, lane = tid & 63;
  int lr = lane & 15, lq = lane >> 4;

  __shared__ __align__(16) unsigned short sK[2][64 * 64];
  __shared__ __align__(16) unsigned short sV[2][64 * 64];
  __shared__ __align__(16) unsigned short sW[128 * 64];
  __shared__ __align__(16) float sK2[2][64];
  __shared__ __align__(16) float sDen[8][16];

  const unsigned short* qbase = P + ((size_t)(b * SEQ + qt * 128)) * PROW + h * 256;
  const unsigned short* kbase = P + ((size_t)(b * SEQ)) * PROW + h * 256 + 64;
  const unsigned short* vtb = Vt + (size_t)bh * 64 * SEQ;
  const float* k2base = nrm + (size_t)(bh * 2 + 1) * SEQ;

  int srow = tid >> 3;
  int scol = ((tid & 7) ^ (srow & 7)) * 8;
  const unsigned short* kSrc = kbase + (size_t)srow * PROW + scol;
  const unsigned short* vSrc = vtb + (size_t)srow * SEQ + scol;

  auto stage_kv = [&](int t, int buf) {
    gload16(kSrc + (size_t)t * 64 * PROW, (char*)&sK[buf][0] + tid * 16);
    gload16(vSrc + (size_t)t * 64, (char*)&sV[buf][0] + tid * 16);
    if (w == 0) gload4(k2base + t * 64 + lane, (char*)&sK2[buf][0] + lane * 4);
  };

  stage_kv(0, 0);
  stage_kv(1, 1);
  int qrow = 16 * w + lr;
  bf16x8 qf[2];
#pragma unroll
  for (int ks = 0; ks < 2; ks++)
    qf[ks] = *(const bf16x8*)(qbase + (size_t)qrow * PROW + ks * 64 + 8 * lq);
  float q2 = nrm[(size_t)(bh * 2) * SEQ + qt * 128 + qrow];
  asm volatile("" ::"v"(q2));
  __syncthreads();

  f32x4 num[4] = {};
  float den = 0.f;
  char* wrow = (char*)sW + qrow * 128;

  for (int kt = 0; kt < NT; kt++) {
    int cur = kt & 1;
    if (kt == NT - 1)
      asm volatile("s_waitcnt vmcnt(0)" ::: "memory");
    else if (w == 0)
      asm volatile("s_waitcnt vmcnt(3)" ::: "memory");
    else
      asm volatile("s_waitcnt vmcnt(2)" ::: "memory");
    __builtin_amdgcn_sched_barrier(0);
    __builtin_amdgcn_s_barrier();
    __builtin_amdgcn_sched_barrier(0);

    f32x4 st[4] = {};
    __builtin_amdgcn_s_setprio(1);
#pragma unroll
    for (int fk = 0; fk < 4; fk++) {
      int row = 16 * fk + lr;
      const char* krow = (const char*)&sK[cur][0] + row * 128;
      bf16x8 kf0 = *(const bf16x8*)(krow + ((lq * 16) ^ ((row & 7) << 4)));
      bf16x8 kf1 = *(const bf16x8*)(krow + ((64 + lq * 16) ^ ((row & 7) << 4)));
      st[fk] = MFMA16(kf0, qf[0], st[fk]);
      st[fk] = MFMA16(kf1, qf[1], st[fk]);
    }
    __builtin_amdgcn_s_setprio(0);

#pragma unroll
    for (int fk = 0; fk < 4; fk++) {
      f32x4 k2v = *(const f32x4*)&sK2[cur][16 * fk + 4 * lq];
      float w0 = __builtin_amdgcn_rcpf(fmaxf(fmaf(-2.f, st[fk][0], q2 + k2v[0]), 1e-8f));
      float w1 = __builtin_amdgcn_rcpf(fmaxf(fmaf(-2.f, st[fk][1], q2 + k2v[1]), 1e-8f));
      float w2 = __builtin_amdgcn_rcpf(fmaxf(fmaf(-2.f, st[fk][2], q2 + k2v[2]), 1e-8f));
      float w3 = __builtin_amdgcn_rcpf(fmaxf(fmaf(-2.f, st[fk][3], q2 + k2v[3]), 1e-8f));
      den += (w0 + w1) + (w2 + w3);
      uint2 pp;
      pp.x = cvt_pk_bf16(w0, w1);
      pp.y = cvt_pk_bf16(w2, w3);
      *(uint2*)(wrow + ((32 * fk + 8 * lq) ^ ((lr & 7) << 4))) = pp;
    }

    __builtin_amdgcn_s_setprio(1);
#pragma unroll
    for (int ks = 0; ks < 2; ks++) {
      bf16x8 aw = *(const bf16x8*)(wrow + ((64 * ks + 16 * lq) ^ ((lr & 7) << 4)));
#pragma unroll
      for (int fn = 0; fn < 4; fn++) {
        int row = 16 * fn + lr;
        bf16x8 bv = *(const bf16x8*)((const char*)&sV[cur][0] + row * 128 +
                                     ((64 * ks + 16 * lq) ^ ((row & 7) << 4)));
        num[fn] = MFMA16(aw, bv, num[fn]);
      }
    }
    __builtin_amdgcn_s_setprio(0);

    __builtin_amdgcn_sched_barrier(0);
    __builtin_amdgcn_s_barrier();
    __builtin_amdgcn_sched_barrier(0);
    if (kt + 2 < NT) stage_kv(kt + 2, cur);
  }

  den += __shfl_xor(den, 16);
  den += __shfl_xor(den, 32);
  if (lq == 0) sDen[w][lr] = den;
  __syncthreads();
  f32x4 dv = *(const f32x4*)&sDen[w][4 * lq];
  f32x4 rdv;
#pragma unroll
  for (int r = 0; r < 4; r++) rdv[r] = __builtin_amdgcn_rcpf(dv[r] + SHEP_EPS);

  const unsigned short* gbase = qbase + 192;
#pragma unroll
  for (int fn = 0; fn < 4; fn++) {
    int c = 16 * fn + lr;
#pragma unroll
    for (int r = 0; r < 4; r++) {
      int ql = 16 * w + 4 * lq + r;
      float g = bf2f(gbase[(size_t)ql * PROW + c]);
      float a = num[fn][r] * rdv[r];
      O[((size_t)(b * SEQ + qt * 128 + ql)) * D_MODEL + h * DH + c] = f2bf(g * a);
    }
  }
}

extern "C" void kernel_launch(void* const* d_in, const int* in_sizes, int n_in,
                              void* d_out, int out_size, void* d_ws, size_t ws_size,
                              hipStream_t stream) {
  const float* X = (const float*)d_in[0];
  const float* W_in = (const float*)d_in[1];
  const float* b_in = (const float*)d_in[2];
  const float* W_out = (const float*)d_in[3];
  const float* b_out = (const float*)d_in[4];
  float* out = (float*)d_out;

  // ws layout:
  //   [0,8MB):    Xn (bf16) -> numP0 (split-0 partials) -> O (combined, in-place)
  //   [8,16MB):   Wi bf16   -> Vt
  //   [16,18MB):  Wo bf16
  //   [18,50MB):  P = QKVG; V-slice (dead after transv) reused as numP1
  //   [50,50.5MB): q2/k2 norms (f32)
  //   [50.5,51MB): denP (f32, split partial dens) -- only if ws_size allows
  char* ws = (char*)d_ws;
  unsigned short* Xn = (unsigned short*)(ws);
  unsigned short* O = (unsigned short*)(ws);
  unsigned short* Wi = (unsigned short*)(ws + ((size_t)8 << 20));
  unsigned short* Vt = (unsigned short*)(ws + ((size_t)8 << 20));
  unsigned short* Wo = (unsigned short*)(ws + ((size_t)16 << 20));
  unsigned short* P = (unsigned short*)(ws + ((size_t)18 << 20));
  float* nrm = (float*)(ws + ((size_t)50 << 20));
  float* denP = (float*)(ws + ((size_t)50 << 20) + ((size_t)512 << 10));

  ln_kernel<<<NTOK, 256, 0, stream>>>(X, Xn);
  cvt_both_kernel<<<5120, 256, 0, stream>>>(W_in, W_out, Wi);
  gemm_p_kernel<<<dim3(32, 32), 256, 0, stream>>>(Xn, Wi, b_in, P, 4096, 4096, 1024);
  transv_kernel<<<dim3(32, 32), 256, 0, stream>>>(P, Vt);
  norms_kernel<<<512, 256, 0, stream>>>(P, nrm);
  if (ws_size >= ((size_t)51 << 20)) {
    attn_split_kernel<<<dim3(16, 32, 2), 256, 0, stream>>>(P, Vt, nrm, O, P, denP);
    combine_kernel<<<2048, 256, 0, stream>>>(O, P, denP);
  } else {
    attn_kernel<<<dim3(16, 32), 512, 0, stream>>>(P, Vt, nrm, O);
  }
  gemm_out_kernel<<<dim3(8, 32), 256, 0, stream>>>(O, Wo, b_out, X, out, 4096, 1024, 1024);
}

// Round 15
// 147.887 us; speedup vs baseline: 1.0954x; 1.0954x over previous
//
#include <hip/hip_runtime.h>

#define SEQ 2048
#define D_MODEL 1024
#define NTOK 4096
#define PROW 4096
#define DH 64
#define LN_EPS 1e-5f
#define SHEP_EPS 1e-4f

typedef __attribute__((ext_vector_type(8))) short bf16x8;
typedef __attribute__((ext_vector_type(4))) short s16x4;
typedef __attribute__((ext_vector_type(4))) float f32x4;

__device__ __forceinline__ unsigned short f2bf(float f) {
  union { float f; unsigned u; } v; v.f = f;
  unsigned r = v.u + 0x7fffu + ((v.u >> 16) & 1u);
  return (unsigned short)(r >> 16);
}
__device__ __forceinline__ float bf2f(unsigned short s) {
  union { unsigned u; float f; } v; v.u = ((unsigned)s) << 16;
  return v.f;
}
__device__ __forceinline__ void gload16(const void* g, void* l) {
  __builtin_amdgcn_global_load_lds(
      (const __attribute__((address_space(1))) unsigned int*)g,
      (__attribute__((address_space(3))) unsigned int*)l, 16, 0, 0);
}
__device__ __forceinline__ void gload4(const void* g, void* l) {
  __builtin_amdgcn_global_load_lds(
      (const __attribute__((address_space(1))) unsigned int*)g,
      (__attribute__((address_space(3))) unsigned int*)l, 4, 0, 0);
}
__device__ __forceinline__ unsigned cvt_pk_bf16(float lo, float hi) {
  unsigned r;
  asm("v_cvt_pk_bf16_f32 %0, %1, %2" : "=v"(r) : "v"(lo), "v"(hi));
  return r;
}
#define MFMA16(a, b, c) __builtin_amdgcn_mfma_f32_16x16x32_bf16(a, b, c, 0, 0, 0)

// XCD-aware bijective block swizzle (T1): valid since nwg % 8 == 0.
__device__ __forceinline__ int xcd_swizzle(int linear, int nwg) {
  int cpx = nwg >> 3;
  return (linear & 7) * cpx + (linear >> 3);
}

// ---------------- fused LayerNorm + weight f32->bf16 convert ----------------
// blocks [0,4096): LN row -> Xn.  blocks [4096,9216): cvt W_in|W_out -> Wi (contig).
__global__ __launch_bounds__(256) void ln_cvt_kernel(
    const float* __restrict__ X, unsigned short* __restrict__ Xn,
    const float* __restrict__ Win, const float* __restrict__ Wout,
    unsigned short* __restrict__ Wdst) {
  int tid = threadIdx.x;
  if (blockIdx.x < NTOK) {
    int row = blockIdx.x;
    const float4* xr = (const float4*)(X + (size_t)row * D_MODEL);
    float4 v = xr[tid];
    float s = v.x + v.y + v.z + v.w;
    float s2 = v.x * v.x + v.y * v.y + v.z * v.z + v.w * v.w;
#pragma unroll
    for (int off = 32; off > 0; off >>= 1) {
      s += __shfl_down(s, off);
      s2 += __shfl_down(s2, off);
    }
    __shared__ float red[8];
    __shared__ float mb[2];
    int wv = tid >> 6;
    if ((tid & 63) == 0) { red[wv] = s; red[4 + wv] = s2; }
    __syncthreads();
    if (tid == 0) {
      float ts = red[0] + red[1] + red[2] + red[3];
      float t2 = red[4] + red[5] + red[6] + red[7];
      float mu = ts * (1.f / D_MODEL);
      float var = t2 * (1.f / D_MODEL) - mu * mu;
      mb[0] = mu;
      mb[1] = rsqrtf(var + LN_EPS);
    }
    __syncthreads();
    float mu = mb[0], rs = mb[1];
    s16x4 o;
    o[0] = (short)f2bf((v.x - mu) * rs);
    o[1] = (short)f2bf((v.y - mu) * rs);
    o[2] = (short)f2bf((v.z - mu) * rs);
    o[3] = (short)f2bf((v.w - mu) * rs);
    ((s16x4*)(Xn + (size_t)row * D_MODEL))[tid] = o;
  } else {
    const int N1 = (4096 * 1024) / 4;
    const int N2 = (1024 * 1024) / 4;
    int i = (blockIdx.x - NTOK) * 256 + tid;
    if (i >= N1 + N2) return;
    float4 v = (i < N1) ? ((const float4*)Win)[i] : ((const float4*)Wout)[i - N1];
    s16x4 o;
    o[0] = (short)f2bf(v.x);
    o[1] = (short)f2bf(v.y);
    o[2] = (short)f2bf(v.z);
    o[3] = (short)f2bf(v.w);
    ((s16x4*)Wdst)[i] = o;
  }
}

// ---------------- GEMM (NT, bf16 in, bf16 out + bias) : P = Xn*Wi^T + b ----------------
// BK=64 K-steps; LDS tiles [128][64] bf16 = 128-B rows with 16-B-group XOR
// swizzle g^=(row&7): conflict-free ds_read_b128 (r8-verified: bank-conflict
// counter collapse). Pre-swizzled global source + same XOR on frag reads.
__global__ __launch_bounds__(256) void gemm_p_kernel(
    const unsigned short* __restrict__ A, const unsigned short* __restrict__ B,
    const float* __restrict__ bias, unsigned short* __restrict__ C,
    int M, int N, int K) {
  __shared__ __align__(16) unsigned short sA[128 * 64];
  __shared__ __align__(16) unsigned short sB[128 * 64];
  int tid = threadIdx.x;
  int nwg = gridDim.x * gridDim.y;
  int swz = xcd_swizzle(blockIdx.y * gridDim.x + blockIdx.x, nwg);
  int m0 = (swz / gridDim.x) * 128, n0 = (swz % gridDim.x) * 128;
  int wv = tid >> 6, lane = tid & 63;
  int wr = wv >> 1, wc = wv & 1;
  int lr = lane & 15, lq = lane >> 4;
  f32x4 acc[4][4] = {};
  for (int k0 = 0; k0 < K; k0 += 64) {
#pragma unroll
    for (int it = 0; it < 4; it++) {
      int c = tid + it * 256;
      int row = c >> 3;
      int col = ((c & 7) ^ (row & 7)) * 8;
      gload16(A + (size_t)(m0 + row) * K + k0 + col, (char*)sA + c * 16);
      gload16(B + (size_t)(n0 + row) * K + k0 + col, (char*)sB + c * 16);
    }
    __syncthreads();
#pragma unroll
    for (int ks = 0; ks < 2; ks++) {
      bf16x8 af[4], bfr[4];
#pragma unroll
      for (int m = 0; m < 4; m++) {
        int row = wr * 64 + m * 16 + lr;
        af[m] = *(const bf16x8*)((const char*)sA + row * 128 +
                                 (((ks * 4 + lq) ^ (lr & 7)) * 16));
      }
#pragma unroll
      for (int n = 0; n < 4; n++) {
        int row = wc * 64 + n * 16 + lr;
        bfr[n] = *(const bf16x8*)((const char*)sB + row * 128 +
                                  (((ks * 4 + lq) ^ (lr & 7)) * 16));
      }
#pragma unroll
      for (int m = 0; m < 4; m++)
#pragma unroll
        for (int n = 0; n < 4; n++)
          acc[m][n] = MFMA16(af[m], bfr[n], acc[m][n]);
    }
    __syncthreads();
  }
#pragma unroll
  for (int m = 0; m < 4; m++) {
    int row = m0 + wr * 64 + m * 16 + lq * 4;
#pragma unroll
    for (int n = 0; n < 4; n++) {
      int col = n0 + wc * 64 + n * 16 + lr;
      float bv = bias[col];
#pragma unroll
      for (int r = 0; r < 4; r++)
        C[(size_t)(row + r) * N + col] = f2bf(acc[m][n][r] + bv);
    }
  }
}

// ---------------- GEMM (NT) + residual + bias, f32 out : out = X + O*Wo^T + b ----------------
__global__ __launch_bounds__(256) void gemm_out_kernel(
    const unsigned short* __restrict__ A, const unsigned short* __restrict__ B,
    const float* __restrict__ bias, const float* __restrict__ Xres,
    float* __restrict__ Out, int M, int N, int K) {
  __shared__ __align__(16) unsigned short sA[128 * 64];
  __shared__ __align__(16) unsigned short sB[128 * 64];
  int tid = threadIdx.x;
  int nwg = gridDim.x * gridDim.y;
  int swz = xcd_swizzle(blockIdx.y * gridDim.x + blockIdx.x, nwg);
  int m0 = (swz / gridDim.x) * 128, n0 = (swz % gridDim.x) * 128;
  int wv = tid >> 6, lane = tid & 63;
  int wr = wv >> 1, wc = wv & 1;
  int lr = lane & 15, lq = lane >> 4;
  f32x4 acc[4][4] = {};
  for (int k0 = 0; k0 < K; k0 += 64) {
#pragma unroll
    for (int it = 0; it < 4; it++) {
      int c = tid + it * 256;
      int row = c >> 3;
      int col = ((c & 7) ^ (row & 7)) * 8;
      gload16(A + (size_t)(m0 + row) * K + k0 + col, (char*)sA + c * 16);
      gload16(B + (size_t)(n0 + row) * K + k0 + col, (char*)sB + c * 16);
    }
    __syncthreads();
#pragma unroll
    for (int ks = 0; ks < 2; ks++) {
      bf16x8 af[4], bfr[4];
#pragma unroll
      for (int m = 0; m < 4; m++) {
        int row = wr * 64 + m * 16 + lr;
        af[m] = *(const bf16x8*)((const char*)sA + row * 128 +
                                 (((ks * 4 + lq) ^ (lr & 7)) * 16));
      }
#pragma unroll
      for (int n = 0; n < 4; n++) {
        int row = wc * 64 + n * 16 + lr;
        bfr[n] = *(const bf16x8*)((const char*)sB + row * 128 +
                                  (((ks * 4 + lq) ^ (lr & 7)) * 16));
      }
#pragma unroll
      for (int m = 0; m < 4; m++)
#pragma unroll
        for (int n = 0; n < 4; n++)
          acc[m][n] = MFMA16(af[m], bfr[n], acc[m][n]);
    }
    __syncthreads();
  }
#pragma unroll
  for (int m = 0; m < 4; m++) {
    int row = m0 + wr * 64 + m * 16 + lq * 4;
#pragma unroll
    for (int n = 0; n < 4; n++) {
      int col = n0 + wc * 64 + n * 16 + lr;
      float bv = bias[col];
#pragma unroll
      for (int r = 0; r < 4; r++) {
        size_t idx = (size_t)(row + r) * N + col;
        Out[idx] = Xres[idx] + acc[m][n][r] + bv;
      }
    }
  }
}

// ---------------- fused V transpose + q2/k2 norms ----------------
// Block (kt,bh): (a) transpose V slice of tokens kt*64..+63 into Vt[bh];
// (b) compute q2 (Q-slice) and k2 (K-slice) row-norms for the same tokens.
__global__ __launch_bounds__(256) void transv_norms_kernel(
    const unsigned short* __restrict__ P, unsigned short* __restrict__ Vt,
    float* __restrict__ nrm) {
  int kt = blockIdx.x;
  int bh = blockIdx.y;
  int b = bh >> 4, h = bh & 15;
  __shared__ unsigned short sT[64][72];
  int tid = threadIdx.x;
  const unsigned short* vbase = P + ((size_t)(b * SEQ + kt * 64)) * PROW + h * 256 + 128;
#pragma unroll
  for (int it = 0; it < 2; it++) {
    int c = tid + it * 256;
    int k = c >> 3, c0 = (c & 7) * 8;
    uint4 u = *(const uint4*)(vbase + (size_t)k * PROW + c0);
    unsigned e[4] = {u.x, u.y, u.z, u.w};
#pragma unroll
    for (int j = 0; j < 4; j++) {
      sT[c0 + 2 * j][k] = (unsigned short)(e[j] & 0xffffu);
      sT[c0 + 2 * j + 1][k] = (unsigned short)(e[j] >> 16);
    }
  }
  // norms: threads 0..127 -> (which = t>>6, token = kt*64 + (t&63))
  if (tid < 128) {
    int which = tid >> 6, tok = tid & 63;
    const unsigned short* p =
        P + ((size_t)(b * SEQ + kt * 64 + tok)) * PROW + h * 256 + which * 64;
    const uint4* pv = (const uint4*)p;
    float acc = 0.f;
#pragma unroll
    for (int i = 0; i < 8; i++) {
      uint4 u = pv[i];
      unsigned arr[4] = {u.x, u.y, u.z, u.w};
#pragma unroll
      for (int j = 0; j < 4; j++) {
        float lo = __uint_as_float(arr[j] << 16);
        float hi = __uint_as_float(arr[j] & 0xffff0000u);
        acc += lo * lo + hi * hi;
      }
    }
    nrm[(size_t)(bh * 2 + which) * SEQ + kt * 64 + tok] = acc;
  }
  __syncthreads();
  unsigned short* obase = Vt + (size_t)bh * 64 * SEQ + kt * 64;
#pragma unroll
  for (int it = 0; it < 2; it++) {
    int cc = tid + it * 256;
    int crow = cc >> 3, k0 = (cc & 7) * 8;
    uint4 o;
    unsigned short e[8];
#pragma unroll
    for (int j = 0; j < 8; j++) e[j] = sT[crow][k0 + j];
    o.x = (unsigned)e[0] | ((unsigned)e[1] << 16);
    o.y = (unsigned)e[2] | ((unsigned)e[3] << 16);
    o.z = (unsigned)e[4] | ((unsigned)e[5] << 16);
    o.w = (unsigned)e[6] | ((unsigned)e[7] << 16);
    *(uint4*)(obase + (size_t)crow * SEQ + k0) = o;
  }
}

// ---------------- Shepard attention (8 waves x 16 q-rows) -- r11 champion (62.8us) ----------------
// Q frags from global; K/V double-buffered via counted-vmcnt pipeline:
//   prologue: stage tiles 0,1; __syncthreads (counts -> 0)
//   iter t: wait vmcnt(2|3) -> s_barrier -> compute(t) -> s_barrier -> stage(t+2).
// sW wave-private; den via shfl+sDen; setprio around MFMA clusters.
__global__ __launch_bounds__(512) void attn_kernel(
    const unsigned short* __restrict__ P, const unsigned short* __restrict__ Vt,
    const float* __restrict__ nrm, unsigned short* __restrict__ O) {
  const int NT = SEQ / 64;
  int qt = blockIdx.x, bh = blockIdx.y;
  int b = bh >> 4, h = bh & 15;
  int tid = threadIdx.x;
  int w = tid >> 6, lane = tid & 63;
  int lr = lane & 15, lq = lane >> 4;

  __shared__ __align__(16) unsigned short sK[2][64 * 64];
  __shared__ __align__(16) unsigned short sV[2][64 * 64];
  __shared__ __align__(16) unsigned short sW[128 * 64];
  __shared__ __align__(16) float sK2[2][64];
  __shared__ __align__(16) float sDen[8][16];

  const unsigned short* qbase = P + ((size_t)(b * SEQ + qt * 128)) * PROW + h * 256;
  const unsigned short* kbase = P + ((size_t)(b * SEQ)) * PROW + h * 256 + 64;
  const unsigned short* vtb = Vt + (size_t)bh * 64 * SEQ;
  const float* k2base = nrm + (size_t)(bh * 2 + 1) * SEQ;

  int srow = tid >> 3;
  int scol = ((tid & 7) ^ (srow & 7)) * 8;
  const unsigned short* kSrc = kbase + (size_t)srow * PROW + scol;
  const unsigned short* vSrc = vtb + (size_t)srow * SEQ + scol;

  auto stage_kv = [&](int t, int buf) {
    gload16(kSrc + (size_t)t * 64 * PROW, (char*)&sK[buf][0] + tid * 16);
    gload16(vSrc + (size_t)t * 64, (char*)&sV[buf][0] + tid * 16);
    if (w == 0) gload4(k2base + t * 64 + lane, (char*)&sK2[buf][0] + lane * 4);
  };

  stage_kv(0, 0);
  stage_kv(1, 1);
  int qrow = 16 * w + lr;
  bf16x8 qf[2];
#pragma unroll
  for (int ks = 0; ks < 2; ks++)
    qf[ks] = *(const bf16x8*)(qbase + (size_t)qrow * PROW + ks * 64 + 8 * lq);
  float q2 = nrm[(size_t)(bh * 2) * SEQ + qt * 128 + qrow];
  asm volatile("" ::"v"(q2));
  __syncthreads();

  f32x4 num[4] = {};
  float den = 0.f;
  char* wrow = (char*)sW + qrow * 128;

  for (int kt = 0; kt < NT; kt++) {
    int cur = kt & 1;
    if (kt == NT - 1)
      asm volatile("s_waitcnt vmcnt(0)" ::: "memory");
    else if (w == 0)
      asm volatile("s_waitcnt vmcnt(3)" ::: "memory");
    else
      asm volatile("s_waitcnt vmcnt(2)" ::: "memory");
    __builtin_amdgcn_sched_barrier(0);
    __builtin_amdgcn_s_barrier();
    __builtin_amdgcn_sched_barrier(0);

    f32x4 st[4] = {};
    __builtin_amdgcn_s_setprio(1);
#pragma unroll
    for (int fk = 0; fk < 4; fk++) {
      int row = 16 * fk + lr;
      const char* krow = (const char*)&sK[cur][0] + row * 128;
      bf16x8 kf0 = *(const bf16x8*)(krow + ((lq * 16) ^ ((row & 7) << 4)));
      bf16x8 kf1 = *(const bf16x8*)(krow + ((64 + lq * 16) ^ ((row & 7) << 4)));
      st[fk] = MFMA16(kf0, qf[0], st[fk]);
      st[fk] = MFMA16(kf1, qf[1], st[fk]);
    }
    __builtin_amdgcn_s_setprio(0);

#pragma unroll
    for (int fk = 0; fk < 4; fk++) {
      f32x4 k2v = *(const f32x4*)&sK2[cur][16 * fk + 4 * lq];
      float w0 = __builtin_amdgcn_rcpf(fmaxf(fmaf(-2.f, st[fk][0], q2 + k2v[0]), 1e-8f));
      float w1 = __builtin_amdgcn_rcpf(fmaxf(fmaf(-2.f, st[fk][1], q2 + k2v[1]), 1e-8f));
      float w2 = __builtin_amdgcn_rcpf(fmaxf(fmaf(-2.f, st[fk][2], q2 + k2v[2]), 1e-8f));
      float w3 = __builtin_amdgcn_rcpf(fmaxf(fmaf(-2.f, st[fk][3], q2 + k2v[3]), 1e-8f));
      den += (w0 + w1) + (w2 + w3);
      uint2 pp;
      pp.x = cvt_pk_bf16(w0, w1);
      pp.y = cvt_pk_bf16(w2, w3);
      *(uint2*)(wrow + ((32 * fk + 8 * lq) ^ ((lr & 7) << 4))) = pp;
    }

    __builtin_amdgcn_s_setprio(1);
#pragma unroll
    for (int ks = 0; ks < 2; ks++) {
      bf16x8 aw = *(const bf16x8*)(wrow + ((64 * ks + 16 * lq) ^ ((lr & 7) << 4)));
#pragma unroll
      for (int fn = 0; fn < 4; fn++) {
        int row = 16 * fn + lr;
        bf16x8 bv = *(const bf16x8*)((const char*)&sV[cur][0] + row * 128 +
                                     ((64 * ks + 16 * lq) ^ ((row & 7) << 4)));
        num[fn] = MFMA16(aw, bv, num[fn]);
      }
    }
    __builtin_amdgcn_s_setprio(0);

    __builtin_amdgcn_sched_barrier(0);
    __builtin_amdgcn_s_barrier();
    __builtin_amdgcn_sched_barrier(0);
    if (kt + 2 < NT) stage_kv(kt + 2, cur);
  }

  den += __shfl_xor(den, 16);
  den += __shfl_xor(den, 32);
  if (lq == 0) sDen[w][lr] = den;
  __syncthreads();
  f32x4 dv = *(const f32x4*)&sDen[w][4 * lq];
  f32x4 rdv;
#pragma unroll
  for (int r = 0; r < 4; r++) rdv[r] = __builtin_amdgcn_rcpf(dv[r] + SHEP_EPS);

  const unsigned short* gbase = qbase + 192;
#pragma unroll
  for (int fn = 0; fn < 4; fn++) {
    int c = 16 * fn + lr;
#pragma unroll
    for (int r = 0; r < 4; r++) {
      int ql = 16 * w + 4 * lq + r;
      float g = bf2f(gbase[(size_t)ql * PROW + c]);
      float a = num[fn][r] * rdv[r];
      O[((size_t)(b * SEQ + qt * 128 + ql)) * D_MODEL + h * DH + c] = f2bf(g * a);
    }
  }
}

extern "C" void kernel_launch(void* const* d_in, const int* in_sizes, int n_in,
                              void* d_out, int out_size, void* d_ws, size_t ws_size,
                              hipStream_t stream) {
  const float* X = (const float*)d_in[0];
  const float* W_in = (const float*)d_in[1];
  const float* b_in = (const float*)d_in[2];
  const float* W_out = (const float*)d_in[3];
  const float* b_out = (const float*)d_in[4];
  float* out = (float*)d_out;

  // ws layout:
  //   [0,8MB):    Xn (bf16) -> reused as O (gated attn output, bf16)
  //   [8,16MB):   Wi bf16   -> reused as Vt (transposed V, bf16)
  //   [16,18MB):  Wo bf16 (contiguous after Wi -> fused cvt)
  //   [18,50MB):  P = QKVG (bf16, [4096][4096])
  //   [50MB,+512K): q2/k2 norms (f32)
  char* ws = (char*)d_ws;
  unsigned short* Xn = (unsigned short*)(ws);
  unsigned short* O = (unsigned short*)(ws);
  unsigned short* Wi = (unsigned short*)(ws + ((size_t)8 << 20));
  unsigned short* Vt = (unsigned short*)(ws + ((size_t)8 << 20));
  unsigned short* Wo = (unsigned short*)(ws + ((size_t)16 << 20));
  unsigned short* P = (unsigned short*)(ws + ((size_t)18 << 20));
  float* nrm = (float*)(ws + ((size_t)50 << 20));

  ln_cvt_kernel<<<NTOK + 5120, 256, 0, stream>>>(X, Xn, W_in, W_out, Wi);
  gemm_p_kernel<<<dim3(32, 32), 256, 0, stream>>>(Xn, Wi, b_in, P, 4096, 4096, 1024);
  transv_norms_kernel<<<dim3(32, 32), 256, 0, stream>>>(P, Vt, nrm);
  attn_kernel<<<dim3(16, 32), 512, 0, stream>>>(P, Vt, nrm, O);
  gemm_out_kernel<<<dim3(8, 32), 256, 0, stream>>>(O, Wo, b_out, X, out, 4096, 1024, 1024);
}

// Round 16
// 141.725 us; speedup vs baseline: 1.1430x; 1.0435x over previous
//
#include <hip/hip_runtime.h>

#define SEQ 2048
#define D_MODEL 1024
#define NTOK 4096
#define PROW 4096
#define DH 64
#define LN_EPS 1e-5f
#define SHEP_EPS 1e-4f

typedef __attribute__((ext_vector_type(8))) short bf16x8;
typedef __attribute__((ext_vector_type(4))) short s16x4;
typedef __attribute__((ext_vector_type(4))) float f32x4;

__device__ __forceinline__ unsigned short f2bf(float f) {
  union { float f; unsigned u; } v; v.f = f;
  unsigned r = v.u + 0x7fffu + ((v.u >> 16) & 1u);
  return (unsigned short)(r >> 16);
}
__device__ __forceinline__ float bf2f(unsigned short s) {
  union { unsigned u; float f; } v; v.u = ((unsigned)s) << 16;
  return v.f;
}
__device__ __forceinline__ void gload16(const void* g, void* l) {
  __builtin_amdgcn_global_load_lds(
      (const __attribute__((address_space(1))) unsigned int*)g,
      (__attribute__((address_space(3))) unsigned int*)l, 16, 0, 0);
}
__device__ __forceinline__ void gload4(const void* g, void* l) {
  __builtin_amdgcn_global_load_lds(
      (const __attribute__((address_space(1))) unsigned int*)g,
      (__attribute__((address_space(3))) unsigned int*)l, 4, 0, 0);
}
__device__ __forceinline__ unsigned cvt_pk_bf16(float lo, float hi) {
  unsigned r;
  asm("v_cvt_pk_bf16_f32 %0, %1, %2" : "=v"(r) : "v"(lo), "v"(hi));
  return r;
}
#define MFMA16(a, b, c) __builtin_amdgcn_mfma_f32_16x16x32_bf16(a, b, c, 0, 0, 0)

// XCD-aware bijective block swizzle (T1): valid since nwg % 8 == 0.
__device__ __forceinline__ int xcd_swizzle(int linear, int nwg) {
  int cpx = nwg >> 3;
  return (linear & 7) * cpx + (linear >> 3);
}

// ---------------- fused LayerNorm + weight f32->bf16 convert ----------------
__global__ __launch_bounds__(256) void ln_cvt_kernel(
    const float* __restrict__ X, unsigned short* __restrict__ Xn,
    const float* __restrict__ Win, const float* __restrict__ Wout,
    unsigned short* __restrict__ Wdst) {
  int tid = threadIdx.x;
  if (blockIdx.x < NTOK) {
    int row = blockIdx.x;
    const float4* xr = (const float4*)(X + (size_t)row * D_MODEL);
    float4 v = xr[tid];
    float s = v.x + v.y + v.z + v.w;
    float s2 = v.x * v.x + v.y * v.y + v.z * v.z + v.w * v.w;
#pragma unroll
    for (int off = 32; off > 0; off >>= 1) {
      s += __shfl_down(s, off);
      s2 += __shfl_down(s2, off);
    }
    __shared__ float red[8];
    __shared__ float mb[2];
    int wv = tid >> 6;
    if ((tid & 63) == 0) { red[wv] = s; red[4 + wv] = s2; }
    __syncthreads();
    if (tid == 0) {
      float ts = red[0] + red[1] + red[2] + red[3];
      float t2 = red[4] + red[5] + red[6] + red[7];
      float mu = ts * (1.f / D_MODEL);
      float var = t2 * (1.f / D_MODEL) - mu * mu;
      mb[0] = mu;
      mb[1] = rsqrtf(var + LN_EPS);
    }
    __syncthreads();
    float mu = mb[0], rs = mb[1];
    s16x4 o;
    o[0] = (short)f2bf((v.x - mu) * rs);
    o[1] = (short)f2bf((v.y - mu) * rs);
    o[2] = (short)f2bf((v.z - mu) * rs);
    o[3] = (short)f2bf((v.w - mu) * rs);
    ((s16x4*)(Xn + (size_t)row * D_MODEL))[tid] = o;
  } else {
    const int N1 = (4096 * 1024) / 4;
    const int N2 = (1024 * 1024) / 4;
    int i = (blockIdx.x - NTOK) * 256 + tid;
    if (i >= N1 + N2) return;
    float4 v = (i < N1) ? ((const float4*)Win)[i] : ((const float4*)Wout)[i - N1];
    s16x4 o;
    o[0] = (short)f2bf(v.x);
    o[1] = (short)f2bf(v.y);
    o[2] = (short)f2bf(v.z);
    o[3] = (short)f2bf(v.w);
    ((s16x4*)Wdst)[i] = o;
  }
}

// ---------------- GEMM (NT, bf16 in, bf16 out + bias) : P = Xn*Wi^T + b ----------------
// BK=64, [128][64] tiles with 16-B-group XOR swizzle (r8-verified conflict-free).
// NEW: r11-certified counted-vmcnt double-buffer pipeline -- prologue stages
// tiles 0,1 + full drain; per step: vmcnt(8) [tile t's 8 uniform gload16/thread
// done; t+1's in flight] -> barrier -> compute(t) -> barrier -> stage(t+2).
// Extra compiler VMEM ops only make vmcnt(N) stricter (never weaker) -> safe.
__global__ __launch_bounds__(256) void gemm_p_kernel(
    const unsigned short* __restrict__ A, const unsigned short* __restrict__ B,
    const float* __restrict__ bias, unsigned short* __restrict__ C,
    int M, int N, int K) {
  __shared__ __align__(16) unsigned short sA[2][128 * 64];
  __shared__ __align__(16) unsigned short sB[2][128 * 64];
  int tid = threadIdx.x;
  int nwg = gridDim.x * gridDim.y;
  int swz = xcd_swizzle(blockIdx.y * gridDim.x + blockIdx.x, nwg);
  int m0 = (swz / gridDim.x) * 128, n0 = (swz % gridDim.x) * 128;
  int wv = tid >> 6, lane = tid & 63;
  int wr = wv >> 1, wc = wv & 1;
  int lr = lane & 15, lq = lane >> 4;
  const int NK = K >> 6;  // 16

  auto stage = [&](int t, int buf) {
#pragma unroll
    for (int it = 0; it < 4; it++) {
      int c = tid + it * 256;
      int row = c >> 3;
      int col = ((c & 7) ^ (row & 7)) * 8;  // pre-swizzled source chunk
      gload16(A + (size_t)(m0 + row) * K + t * 64 + col, (char*)&sA[buf][0] + c * 16);
      gload16(B + (size_t)(n0 + row) * K + t * 64 + col, (char*)&sB[buf][0] + c * 16);
    }
  };

  f32x4 acc[4][4] = {};
  stage(0, 0);
  stage(1, 1);
  __syncthreads();  // full drain: counts start at 0

  for (int t = 0; t < NK; t++) {
    int cur = t & 1;
    if (t == NK - 1)
      asm volatile("s_waitcnt vmcnt(0)" ::: "memory");
    else
      asm volatile("s_waitcnt vmcnt(8)" ::: "memory");
    __builtin_amdgcn_sched_barrier(0);
    __builtin_amdgcn_s_barrier();
    __builtin_amdgcn_sched_barrier(0);

#pragma unroll
    for (int ks = 0; ks < 2; ks++) {
      bf16x8 af[4], bfr[4];
#pragma unroll
      for (int m = 0; m < 4; m++) {
        int row = wr * 64 + m * 16 + lr;
        af[m] = *(const bf16x8*)((const char*)&sA[cur][0] + row * 128 +
                                 (((ks * 4 + lq) ^ (lr & 7)) * 16));
      }
#pragma unroll
      for (int n = 0; n < 4; n++) {
        int row = wc * 64 + n * 16 + lr;
        bfr[n] = *(const bf16x8*)((const char*)&sB[cur][0] + row * 128 +
                                  (((ks * 4 + lq) ^ (lr & 7)) * 16));
      }
#pragma unroll
      for (int m = 0; m < 4; m++)
#pragma unroll
        for (int n = 0; n < 4; n++)
          acc[m][n] = MFMA16(af[m], bfr[n], acc[m][n]);
    }

    __builtin_amdgcn_sched_barrier(0);
    __builtin_amdgcn_s_barrier();  // all waves done reading buffer cur
    __builtin_amdgcn_sched_barrier(0);
    if (t + 2 < NK) stage(t + 2, cur);  // refill freed buffer
  }

#pragma unroll
  for (int m = 0; m < 4; m++) {
    int row = m0 + wr * 64 + m * 16 + lq * 4;
#pragma unroll
    for (int n = 0; n < 4; n++) {
      int col = n0 + wc * 64 + n * 16 + lr;
      float bv = bias[col];
#pragma unroll
      for (int r = 0; r < 4; r++)
        C[(size_t)(row + r) * N + col] = f2bf(acc[m][n][r] + bv);
    }
  }
}

// ---------------- GEMM (NT) + residual + bias, f32 out : out = X + O*Wo^T + b ----------------
// Same counted-vmcnt double-buffer pipeline as gemm_p.
__global__ __launch_bounds__(256) void gemm_out_kernel(
    const unsigned short* __restrict__ A, const unsigned short* __restrict__ B,
    const float* __restrict__ bias, const float* __restrict__ Xres,
    float* __restrict__ Out, int M, int N, int K) {
  __shared__ __align__(16) unsigned short sA[2][128 * 64];
  __shared__ __align__(16) unsigned short sB[2][128 * 64];
  int tid = threadIdx.x;
  int nwg = gridDim.x * gridDim.y;
  int swz = xcd_swizzle(blockIdx.y * gridDim.x + blockIdx.x, nwg);
  int m0 = (swz / gridDim.x) * 128, n0 = (swz % gridDim.x) * 128;
  int wv = tid >> 6, lane = tid & 63;
  int wr = wv >> 1, wc = wv & 1;
  int lr = lane & 15, lq = lane >> 4;
  const int NK = K >> 6;  // 16

  auto stage = [&](int t, int buf) {
#pragma unroll
    for (int it = 0; it < 4; it++) {
      int c = tid + it * 256;
      int row = c >> 3;
      int col = ((c & 7) ^ (row & 7)) * 8;
      gload16(A + (size_t)(m0 + row) * K + t * 64 + col, (char*)&sA[buf][0] + c * 16);
      gload16(B + (size_t)(n0 + row) * K + t * 64 + col, (char*)&sB[buf][0] + c * 16);
    }
  };

  f32x4 acc[4][4] = {};
  stage(0, 0);
  stage(1, 1);
  __syncthreads();

  for (int t = 0; t < NK; t++) {
    int cur = t & 1;
    if (t == NK - 1)
      asm volatile("s_waitcnt vmcnt(0)" ::: "memory");
    else
      asm volatile("s_waitcnt vmcnt(8)" ::: "memory");
    __builtin_amdgcn_sched_barrier(0);
    __builtin_amdgcn_s_barrier();
    __builtin_amdgcn_sched_barrier(0);

#pragma unroll
    for (int ks = 0; ks < 2; ks++) {
      bf16x8 af[4], bfr[4];
#pragma unroll
      for (int m = 0; m < 4; m++) {
        int row = wr * 64 + m * 16 + lr;
        af[m] = *(const bf16x8*)((const char*)&sA[cur][0] + row * 128 +
                                 (((ks * 4 + lq) ^ (lr & 7)) * 16));
      }
#pragma unroll
      for (int n = 0; n < 4; n++) {
        int row = wc * 64 + n * 16 + lr;
        bfr[n] = *(const bf16x8*)((const char*)&sB[cur][0] + row * 128 +
                                  (((ks * 4 + lq) ^ (lr & 7)) * 16));
      }
#pragma unroll
      for (int m = 0; m < 4; m++)
#pragma unroll
        for (int n = 0; n < 4; n++)
          acc[m][n] = MFMA16(af[m], bfr[n], acc[m][n]);
    }

    __builtin_amdgcn_sched_barrier(0);
    __builtin_amdgcn_s_barrier();
    __builtin_amdgcn_sched_barrier(0);
    if (t + 2 < NK) stage(t + 2, cur);
  }

#pragma unroll
  for (int m = 0; m < 4; m++) {
    int row = m0 + wr * 64 + m * 16 + lq * 4;
#pragma unroll
    for (int n = 0; n < 4; n++) {
      int col = n0 + wc * 64 + n * 16 + lr;
      float bv = bias[col];
#pragma unroll
      for (int r = 0; r < 4; r++) {
        size_t idx = (size_t)(row + r) * N + col;
        Out[idx] = Xres[idx] + acc[m][n][r] + bv;
      }
    }
  }
}

// ---------------- fused V transpose + q2/k2 norms ----------------
__global__ __launch_bounds__(256) void transv_norms_kernel(
    const unsigned short* __restrict__ P, unsigned short* __restrict__ Vt,
    float* __restrict__ nrm) {
  int kt = blockIdx.x;
  int bh = blockIdx.y;
  int b = bh >> 4, h = bh & 15;
  __shared__ unsigned short sT[64][72];
  int tid = threadIdx.x;
  const unsigned short* vbase = P + ((size_t)(b * SEQ + kt * 64)) * PROW + h * 256 + 128;
#pragma unroll
  for (int it = 0; it < 2; it++) {
    int c = tid + it * 256;
    int k = c >> 3, c0 = (c & 7) * 8;
    uint4 u = *(const uint4*)(vbase + (size_t)k * PROW + c0);
    unsigned e[4] = {u.x, u.y, u.z, u.w};
#pragma unroll
    for (int j = 0; j < 4; j++) {
      sT[c0 + 2 * j][k] = (unsigned short)(e[j] & 0xffffu);
      sT[c0 + 2 * j + 1][k] = (unsigned short)(e[j] >> 16);
    }
  }
  if (tid < 128) {
    int which = tid >> 6, tok = tid & 63;
    const unsigned short* p =
        P + ((size_t)(b * SEQ + kt * 64 + tok)) * PROW + h * 256 + which * 64;
    const uint4* pv = (const uint4*)p;
    float acc = 0.f;
#pragma unroll
    for (int i = 0; i < 8; i++) {
      uint4 u = pv[i];
      unsigned arr[4] = {u.x, u.y, u.z, u.w};
#pragma unroll
      for (int j = 0; j < 4; j++) {
        float lo = __uint_as_float(arr[j] << 16);
        float hi = __uint_as_float(arr[j] & 0xffff0000u);
        acc += lo * lo + hi * hi;
      }
    }
    nrm[(size_t)(bh * 2 + which) * SEQ + kt * 64 + tok] = acc;
  }
  __syncthreads();
  unsigned short* obase = Vt + (size_t)bh * 64 * SEQ + kt * 64;
#pragma unroll
  for (int it = 0; it < 2; it++) {
    int cc = tid + it * 256;
    int crow = cc >> 3, k0 = (cc & 7) * 8;
    uint4 o;
    unsigned short e[8];
#pragma unroll
    for (int j = 0; j < 8; j++) e[j] = sT[crow][k0 + j];
    o.x = (unsigned)e[0] | ((unsigned)e[1] << 16);
    o.y = (unsigned)e[2] | ((unsigned)e[3] << 16);
    o.z = (unsigned)e[4] | ((unsigned)e[5] << 16);
    o.w = (unsigned)e[6] | ((unsigned)e[7] << 16);
    *(uint4*)(obase + (size_t)crow * SEQ + k0) = o;
  }
}

// ---------------- Shepard attention (8 waves x 16 q-rows) -- r11 champion (62.8us) ----------------
__global__ __launch_bounds__(512) void attn_kernel(
    const unsigned short* __restrict__ P, const unsigned short* __restrict__ Vt,
    const float* __restrict__ nrm, unsigned short* __restrict__ O) {
  const int NT = SEQ / 64;
  int qt = blockIdx.x, bh = blockIdx.y;
  int b = bh >> 4, h = bh & 15;
  int tid = threadIdx.x;
  int w = tid >> 6, lane = tid & 63;
  int lr = lane & 15, lq = lane >> 4;

  __shared__ __align__(16) unsigned short sK[2][64 * 64];
  __shared__ __align__(16) unsigned short sV[2][64 * 64];
  __shared__ __align__(16) unsigned short sW[128 * 64];
  __shared__ __align__(16) float sK2[2][64];
  __shared__ __align__(16) float sDen[8][16];

  const unsigned short* qbase = P + ((size_t)(b * SEQ + qt * 128)) * PROW + h * 256;
  const unsigned short* kbase = P + ((size_t)(b * SEQ)) * PROW + h * 256 + 64;
  const unsigned short* vtb = Vt + (size_t)bh * 64 * SEQ;
  const float* k2base = nrm + (size_t)(bh * 2 + 1) * SEQ;

  int srow = tid >> 3;
  int scol = ((tid & 7) ^ (srow & 7)) * 8;
  const unsigned short* kSrc = kbase + (size_t)srow * PROW + scol;
  const unsigned short* vSrc = vtb + (size_t)srow * SEQ + scol;

  auto stage_kv = [&](int t, int buf) {
    gload16(kSrc + (size_t)t * 64 * PROW, (char*)&sK[buf][0] + tid * 16);
    gload16(vSrc + (size_t)t * 64, (char*)&sV[buf][0] + tid * 16);
    if (w == 0) gload4(k2base + t * 64 + lane, (char*)&sK2[buf][0] + lane * 4);
  };

  stage_kv(0, 0);
  stage_kv(1, 1);
  int qrow = 16 * w + lr;
  bf16x8 qf[2];
#pragma unroll
  for (int ks = 0; ks < 2; ks++)
    qf[ks] = *(const bf16x8*)(qbase + (size_t)qrow * PROW + ks * 64 + 8 * lq);
  float q2 = nrm[(size_t)(bh * 2) * SEQ + qt * 128 + qrow];
  asm volatile("" ::"v"(q2));
  __syncthreads();

  f32x4 num[4] = {};
  float den = 0.f;
  char* wrow = (char*)sW + qrow * 128;

  for (int kt = 0; kt < NT; kt++) {
    int cur = kt & 1;
    if (kt == NT - 1)
      asm volatile("s_waitcnt vmcnt(0)" ::: "memory");
    else if (w == 0)
      asm volatile("s_waitcnt vmcnt(3)" ::: "memory");
    else
      asm volatile("s_waitcnt vmcnt(2)" ::: "memory");
    __builtin_amdgcn_sched_barrier(0);
    __builtin_amdgcn_s_barrier();
    __builtin_amdgcn_sched_barrier(0);

    f32x4 st[4] = {};
    __builtin_amdgcn_s_setprio(1);
#pragma unroll
    for (int fk = 0; fk < 4; fk++) {
      int row = 16 * fk + lr;
      const char* krow = (const char*)&sK[cur][0] + row * 128;
      bf16x8 kf0 = *(const bf16x8*)(krow + ((lq * 16) ^ ((row & 7) << 4)));
      bf16x8 kf1 = *(const bf16x8*)(krow + ((64 + lq * 16) ^ ((row & 7) << 4)));
      st[fk] = MFMA16(kf0, qf[0], st[fk]);
      st[fk] = MFMA16(kf1, qf[1], st[fk]);
    }
    __builtin_amdgcn_s_setprio(0);

#pragma unroll
    for (int fk = 0; fk < 4; fk++) {
      f32x4 k2v = *(const f32x4*)&sK2[cur][16 * fk + 4 * lq];
      float w0 = __builtin_amdgcn_rcpf(fmaxf(fmaf(-2.f, st[fk][0], q2 + k2v[0]), 1e-8f));
      float w1 = __builtin_amdgcn_rcpf(fmaxf(fmaf(-2.f, st[fk][1], q2 + k2v[1]), 1e-8f));
      float w2 = __builtin_amdgcn_rcpf(fmaxf(fmaf(-2.f, st[fk][2], q2 + k2v[2]), 1e-8f));
      float w3 = __builtin_amdgcn_rcpf(fmaxf(fmaf(-2.f, st[fk][3], q2 + k2v[3]), 1e-8f));
      den += (w0 + w1) + (w2 + w3);
      uint2 pp;
      pp.x = cvt_pk_bf16(w0, w1);
      pp.y = cvt_pk_bf16(w2, w3);
      *(uint2*)(wrow + ((32 * fk + 8 * lq) ^ ((lr & 7) << 4))) = pp;
    }

    __builtin_amdgcn_s_setprio(1);
#pragma unroll
    for (int ks = 0; ks < 2; ks++) {
      bf16x8 aw = *(const bf16x8*)(wrow + ((64 * ks + 16 * lq) ^ ((lr & 7) << 4)));
#pragma unroll
      for (int fn = 0; fn < 4; fn++) {
        int row = 16 * fn + lr;
        bf16x8 bv = *(const bf16x8*)((const char*)&sV[cur][0] + row * 128 +
                                     ((64 * ks + 16 * lq) ^ ((row & 7) << 4)));
        num[fn] = MFMA16(aw, bv, num[fn]);
      }
    }
    __builtin_amdgcn_s_setprio(0);

    __builtin_amdgcn_sched_barrier(0);
    __builtin_amdgcn_s_barrier();
    __builtin_amdgcn_sched_barrier(0);
    if (kt + 2 < NT) stage_kv(kt + 2, cur);
  }

  den += __shfl_xor(den, 16);
  den += __shfl_xor(den, 32);
  if (lq == 0) sDen[w][lr] = den;
  __syncthreads();
  f32x4 dv = *(const f32x4*)&sDen[w][4 * lq];
  f32x4 rdv;
#pragma unroll
  for (int r = 0; r < 4; r++) rdv[r] = __builtin_amdgcn_rcpf(dv[r] + SHEP_EPS);

  const unsigned short* gbase = qbase + 192;
#pragma unroll
  for (int fn = 0; fn < 4; fn++) {
    int c = 16 * fn + lr;
#pragma unroll
    for (int r = 0; r < 4; r++) {
      int ql = 16 * w + 4 * lq + r;
      float g = bf2f(gbase[(size_t)ql * PROW + c]);
      float a = num[fn][r] * rdv[r];
      O[((size_t)(b * SEQ + qt * 128 + ql)) * D_MODEL + h * DH + c] = f2bf(g * a);
    }
  }
}

extern "C" void kernel_launch(void* const* d_in, const int* in_sizes, int n_in,
                              void* d_out, int out_size, void* d_ws, size_t ws_size,
                              hipStream_t stream) {
  const float* X = (const float*)d_in[0];
  const float* W_in = (const float*)d_in[1];
  const float* b_in = (const float*)d_in[2];
  const float* W_out = (const float*)d_in[3];
  const float* b_out = (const float*)d_in[4];
  float* out = (float*)d_out;

  // ws layout:
  //   [0,8MB):    Xn (bf16) -> reused as O (gated attn output, bf16)
  //   [8,16MB):   Wi bf16   -> reused as Vt (transposed V, bf16)
  //   [16,18MB):  Wo bf16 (contiguous after Wi -> fused cvt)
  //   [18,50MB):  P = QKVG (bf16, [4096][4096])
  //   [50MB,+512K): q2/k2 norms (f32)
  char* ws = (char*)d_ws;
  unsigned short* Xn = (unsigned short*)(ws);
  unsigned short* O = (unsigned short*)(ws);
  unsigned short* Wi = (unsigned short*)(ws + ((size_t)8 << 20));
  unsigned short* Vt = (unsigned short*)(ws + ((size_t)8 << 20));
  unsigned short* Wo = (unsigned short*)(ws + ((size_t)16 << 20));
  unsigned short* P = (unsigned short*)(ws + ((size_t)18 << 20));
  float* nrm = (float*)(ws + ((size_t)50 << 20));

  ln_cvt_kernel<<<NTOK + 5120, 256, 0, stream>>>(X, Xn, W_in, W_out, Wi);
  gemm_p_kernel<<<dim3(32, 32), 256, 0, stream>>>(Xn, Wi, b_in, P, 4096, 4096, 1024);
  transv_norms_kernel<<<dim3(32, 32), 256, 0, stream>>>(P, Vt, nrm);
  attn_kernel<<<dim3(16, 32), 512, 0, stream>>>(P, Vt, nrm, O);
  gemm_out_kernel<<<dim3(8, 32), 256, 0, stream>>>(O, Wo, b_out, X, out, 4096, 1024, 1024);
}